// Round 2
// baseline (611.489 us; speedup 1.0000x reference)
//
#include <hip/hip_runtime.h>
#include <hip/hip_bf16.h>

typedef unsigned short u16;
typedef __attribute__((ext_vector_type(4))) float f32x4;
typedef __attribute__((ext_vector_type(8))) __bf16 bf16x8;
typedef __attribute__((ext_vector_type(8))) short short8;

constexpr int SEQ = 8192;
constexpr int DM  = 512;
constexpr int HD  = 64;
constexpr int HFF = 2048;

__device__ __forceinline__ float b2f(u16 u){
  union { unsigned int i; float f; } v; v.i = ((unsigned int)u) << 16; return v.f;
}
__device__ __forceinline__ u16 f2b(float f){
  union { float f; unsigned int i; } v; v.f = f;
  unsigned int r = v.i + 0x7FFFu + ((v.i >> 16) & 1u);
  return (u16)(r >> 16);
}

// ---------------- fp32 passthrough copy (output 0), float4 ----------------
__global__ __launch_bounds__(256) void copyf_k(const float* __restrict__ in,
                                               float* __restrict__ out, long n4){
  long i = blockIdx.x * 256L + threadIdx.x;
  if(i < n4) ((f32x4*)out)[i] = ((const f32x4*)in)[i];
}

// ---------------- fp32 -> bf16 convert, 8 elems/thread ----------------
__global__ __launch_bounds__(256) void cvt_k(const float* __restrict__ in,
                                             u16* __restrict__ out, long n8){
  long i = blockIdx.x * 256L + threadIdx.x;
  if(i >= n8) return;
  f32x4 a = ((const f32x4*)in)[i*2];
  f32x4 b = ((const f32x4*)in)[i*2+1];
  u16 ov[8];
  for(int j=0;j<4;j++){ ov[j] = f2b(a[j]); ov[4+j] = f2b(b[j]); }
  ((short8*)out)[i] = *(short8*)ov;
}

// ---------------- 32x32 transpose; IN_F: 1=fp32 input, 0=bf16 input ------
template<int IN_F>
__global__ __launch_bounds__(256) void transpose_k(const void* __restrict__ inp,
                                                   u16* __restrict__ out, int R, int C){
  __shared__ u16 t[32][33];
  int c0 = blockIdx.x*32, r0 = blockIdx.y*32;
  int tx = threadIdx.x, ty = threadIdx.y;     // blockDim (32,8)
  for(int i=0;i<4;i++){
    long idx = (long)(r0+ty+i*8)*C + c0+tx;
    u16 v;
    if constexpr (IN_F) v = f2b(((const float*)inp)[idx]);
    else                v = ((const u16*)inp)[idx];
    t[ty+i*8][tx] = v;
  }
  __syncthreads();
  for(int i=0;i<4;i++) out[(long)(c0+ty+i*8)*R + r0+tx] = t[tx][ty+i*8];
}

// ---------------- w_o head-sum, transposed: outT[n*64+p] = sum_h wo[h*64+p][n]
__global__ __launch_bounds__(256) void wosum_k(const float* __restrict__ wo,
                                               u16* __restrict__ outT){
  int tid = blockIdx.x*256 + threadIdx.x;     // 32768 total
  int n = tid >> 6, p = tid & 63;
  float s = 0.f;
  for(int h=0; h<8; h++) s += wo[(long)(h*64+p)*DM + n];
  outT[n*64+p] = f2b(s);
}

// ---------------- fused residual-add + LayerNorm (row=512, 1 wave/row) ----
// Xa: bf16, Xb: fp32, gamma/beta: fp32. Writes fp32 OutF; if WRITE_BF also bf16 OutB.
template<bool WRITE_BF>
__global__ __launch_bounds__(256) void add_ln(const u16* __restrict__ Xa,
                                              const float* __restrict__ Xb,
                                              const float* __restrict__ G,
                                              const float* __restrict__ Bb,
                                              float* __restrict__ OutF,
                                              u16* __restrict__ OutB){
  int row  = blockIdx.x*4 + (threadIdx.x>>6);
  int lane = threadIdx.x & 63;
  short8 a8 = *(const short8*)&Xa[(long)row*DM + lane*8];
  f32x4 b0 = *(const f32x4*)&Xb[(long)row*DM + lane*8];
  f32x4 b1 = *(const f32x4*)&Xb[(long)row*DM + lane*8 + 4];
  float x[8]; float s=0.f, s2=0.f;
  for(int i=0;i<8;i++){
    float bv = (i<4) ? b0[i] : b1[i-4];
    x[i] = b2f((u16)a8[i]) + bv;
    s += x[i]; s2 += x[i]*x[i];
  }
  for(int o=1;o<64;o<<=1){ s += __shfl_xor(s,o); s2 += __shfl_xor(s2,o); }
  float mu  = s * (1.f/DM);
  float var = s2 * (1.f/DM) - mu*mu;
  float rstd = rsqrtf(var + 1e-5f);
  f32x4 g0 = *(const f32x4*)&G[lane*8];
  f32x4 g1 = *(const f32x4*)&G[lane*8+4];
  f32x4 p0 = *(const f32x4*)&Bb[lane*8];
  f32x4 p1 = *(const f32x4*)&Bb[lane*8+4];
  float of[8]; u16 ob[8];
  for(int i=0;i<8;i++){
    float gv = (i<4)?g0[i]:g1[i-4], bv2 = (i<4)?p0[i]:p1[i-4];
    float v = (x[i]-mu)*rstd*gv + bv2;
    of[i] = v; ob[i] = f2b(v);
  }
  *(f32x4*)&OutF[(long)row*DM + lane*8]     = *(f32x4*)&of[0];
  *(f32x4*)&OutF[(long)row*DM + lane*8 + 4] = *(f32x4*)&of[4];
  if constexpr (WRITE_BF)
    *(short8*)&OutB[(long)row*DM + lane*8] = *(short8*)ob;
}

// ---------------- generic bf16 GEMM: C[M,N] = epi(A[M,K] @ Bt[N,K]^T + bias)
// EPI: 0=none, 1=+bias(fp32), 2=+bias,leakyrelu. 4 waves, BK=64, padded LDS.
template<int BM,int BN,int WR,int WC,int EPI>
__global__ __launch_bounds__(256) void gemm_bt(const u16* __restrict__ A,
                                               const u16* __restrict__ Bt,
                                               u16* __restrict__ C,
                                               const float* __restrict__ bias,
                                               int N, int K, long sB, long sC){
  constexpr int WM = BM/WR, WN = BN/WC;
  constexpr int MF = WM/16, NF = WN/16;
  constexpr int LDK = 72;                       // 64 + 8 pad
  __shared__ u16 As[BM*LDK];
  __shared__ u16 Bs[BN*LDK];

  const int tid = threadIdx.x;
  const int wid = tid >> 6, lane = tid & 63;
  const int g = lane >> 4, lr = lane & 15;
  const int m0 = blockIdx.x * BM;
  const int n0 = blockIdx.y * BN;
  Bt += (long)blockIdx.z * sB;
  C  += (long)blockIdx.z * sC;
  const int wr = wid / WC, wc = wid % WC;

  f32x4 acc[MF][NF];
  for(int m=0;m<MF;m++) for(int n=0;n<NF;n++) acc[m][n] = (f32x4)0.f;

  for(int k0=0; k0<K; k0+=64){
    for(int it=0; it<BM*8/256; ++it){
      int idx = tid + it*256; int r = idx>>3, c8 = idx&7;
      *(short8*)&As[r*LDK + c8*8] = *(const short8*)&A[(long)(m0+r)*K + k0 + c8*8];
    }
    for(int it=0; it<BN*8/256; ++it){
      int idx = tid + it*256; int r = idx>>3, c8 = idx&7;
      *(short8*)&Bs[r*LDK + c8*8] = *(const short8*)&Bt[(long)(n0+r)*K + k0 + c8*8];
    }
    __syncthreads();
    for(int kc=0;kc<2;kc++){
      bf16x8 af[MF], bfr[NF];
      for(int m=0;m<MF;m++) af[m]  = *(const bf16x8*)&As[(wr*WM + m*16 + lr)*LDK + kc*32 + g*8];
      for(int n=0;n<NF;n++) bfr[n] = *(const bf16x8*)&Bs[(wc*WN + n*16 + lr)*LDK + kc*32 + g*8];
      for(int m=0;m<MF;m++)
        for(int n=0;n<NF;n++)
          acc[m][n] = __builtin_amdgcn_mfma_f32_16x16x32_bf16(af[m], bfr[n], acc[m][n], 0,0,0);
    }
    __syncthreads();
  }
  for(int m=0;m<MF;m++){
    int row = m0 + wr*WM + m*16 + g*4;
    for(int n=0;n<NF;n++){
      int col = n0 + wc*WN + n*16 + lr;
      float bv = 0.f;
      if constexpr (EPI>=1) bv = bias[col];
      for(int j=0;j<4;j++){
        float v = acc[m][n][j] + bv;
        if constexpr (EPI==2) v = (v >= 0.f) ? v : 0.01f*v;
        C[(long)(row+j)*N + col] = f2b(v);
      }
    }
  }
}

// ---------------- flash attention, head dim 64, QBLK=64 (4 waves x 16 rows)
// Q:[S,64]  Km:[S,64]  Vt:[64,S] (V transposed)  O:[S,64]
template<bool CAUSAL>
__global__ __launch_bounds__(256) void attn_k(const u16* __restrict__ Q,
                                              const u16* __restrict__ Km,
                                              const u16* __restrict__ Vt,
                                              u16* __restrict__ O){
  constexpr int LDK = 72;
  __shared__ u16 Ks[64*LDK];      // [kv][d]
  __shared__ u16 Vs[64*LDK];      // [d][kv]
  __shared__ u16 Ps[4*16*LDK];    // per-wave P tile [16][64]

  const int tid = threadIdx.x, wid = tid>>6, lane = tid&63;
  const int g = lane>>4, lr = lane&15;
  const int q0 = blockIdx.x * 64;
  const int qrow = q0 + wid*16;

  bf16x8 qf[2];
  for(int kc=0;kc<2;kc++)
    qf[kc] = *(const bf16x8*)&Q[(long)(qrow + lr)*HD + kc*32 + g*8];

  f32x4 o[4]; for(int n=0;n<4;n++) o[n] = (f32x4)0.f;
  float mst[4], lst[4];
  for(int j=0;j<4;j++){ mst[j] = -INFINITY; lst[j] = 0.f; }

  const int ntiles = CAUSAL ? ((int)blockIdx.x + 1) : (SEQ/64);
  for(int t=0; t<ntiles; ++t){
    const int kv0 = t*64;
    __syncthreads();                       // prev iter done with Ks/Vs
    for(int it=0; it<2; ++it){
      int idx = tid + it*256; int r = idx>>3, c8 = idx&7;
      *(short8*)&Ks[r*LDK + c8*8] = *(const short8*)&Km[(long)(kv0+r)*HD + c8*8];
      *(short8*)&Vs[r*LDK + c8*8] = *(const short8*)&Vt[(long)r*SEQ + kv0 + c8*8];
    }
    __syncthreads();

    f32x4 s[4]; for(int n=0;n<4;n++) s[n] = (f32x4)0.f;
    for(int kc=0;kc<2;kc++){
      for(int n=0;n<4;n++){
        bf16x8 kf = *(const bf16x8*)&Ks[(n*16+lr)*LDK + kc*32 + g*8];
        s[n] = __builtin_amdgcn_mfma_f32_16x16x32_bf16(qf[kc], kf, s[n], 0,0,0);
      }
    }
    for(int n=0;n<4;n++)
      for(int j=0;j<4;j++){
        float v = s[n][j]*0.125f;
        if(CAUSAL){
          int col = kv0 + n*16 + lr, row = qrow + g*4 + j;
          if(col > row) v = -INFINITY;
        }
        s[n][j] = v;
      }
    float fac[4], rs[4];
    for(int j=0;j<4;j++){
      float v = fmaxf(fmaxf(s[0][j],s[1][j]), fmaxf(s[2][j],s[3][j]));
      v = fmaxf(v, __shfl_xor(v,1)); v = fmaxf(v, __shfl_xor(v,2));
      v = fmaxf(v, __shfl_xor(v,4)); v = fmaxf(v, __shfl_xor(v,8));
      float mn = fmaxf(mst[j], v);
      fac[j] = __expf(mst[j] - mn);
      mst[j] = mn;
      rs[j] = 0.f;
    }
    for(int n=0;n<4;n++)
      for(int j=0;j<4;j++){
        float p = __expf(s[n][j] - mst[j]);
        rs[j] += p;
        Ps[(wid*16 + g*4 + j)*LDK + n*16 + lr] = f2b(p);
      }
    for(int j=0;j<4;j++){
      float v = rs[j];
      v += __shfl_xor(v,1); v += __shfl_xor(v,2);
      v += __shfl_xor(v,4); v += __shfl_xor(v,8);
      lst[j] = lst[j]*fac[j] + v;
    }
    for(int n=0;n<4;n++)
      for(int j=0;j<4;j++) o[n][j] *= fac[j];
    __syncthreads();                       // P visible (and staging settled)
    for(int kc=0;kc<2;kc++){
      bf16x8 pf = *(const bf16x8*)&Ps[(wid*16 + lr)*LDK + kc*32 + g*8];
      for(int n=0;n<4;n++){
        bf16x8 vf = *(const bf16x8*)&Vs[(n*16+lr)*LDK + kc*32 + g*8];
        o[n] = __builtin_amdgcn_mfma_f32_16x16x32_bf16(pf, vf, o[n], 0,0,0);
      }
    }
  }
  for(int n=0;n<4;n++){
    int col = n*16 + lr;
    for(int j=0;j<4;j++){
      int row = qrow + g*4 + j;
      O[(long)row*HD + col] = f2b(o[n][j] / lst[j]);
    }
  }
}

extern "C" void kernel_launch(void* const* d_in, const int* in_sizes, int n_in,
                              void* d_out, int out_size, void* d_ws, size_t ws_size,
                              hipStream_t stream){
  const float* enc  = (const float*)d_in[0];
  const float* prev = (const float*)d_in[1];
  const float* wq_m = (const float*)d_in[2];
  const float* wk_m = (const float*)d_in[3];
  const float* wv_m = (const float*)d_in[4];
  const float* wq_c = (const float*)d_in[5];
  const float* wk_c = (const float*)d_in[6];
  const float* wv_c = (const float*)d_in[7];
  const float* w_o  = (const float*)d_in[8];
  const float* ln_g = (const float*)d_in[9];
  const float* ln_b = (const float*)d_in[10];
  const float* w1   = (const float*)d_in[11];
  const float* b1   = (const float*)d_in[12];
  const float* w2   = (const float*)d_in[13];
  const float* b2   = (const float*)d_in[14];
  float* out = (float*)d_out;
  u16* ws  = (u16*)d_ws;

  // workspace layout (u16 element offsets)
  u16* wq_m_t = ws;                          //  32768 each, 6 transposed projs
  u16* wk_m_t = wq_m_t + 32768;
  u16* wv_m_t = wk_m_t + 32768;
  u16* wq_c_t = wv_m_t + 32768;
  u16* wk_c_t = wq_c_t + 32768;
  u16* wv_c_t = wk_c_t + 32768;
  u16* wost   = wv_c_t + 32768;              // 512*64
  u16* w1_t   = wost   + 32768;              // 2048*512
  u16* w2_t   = w1_t   + 1048576;            // 512*2048
  u16* enc_b  = w2_t   + 1048576;            // 8192*512 bf16
  u16* prev_b = enc_b  + 4194304;
  u16* q_m    = prev_b + 4194304;            // 8192*64 each
  u16* k_m    = q_m    + 524288;
  u16* v_m    = k_m    + 524288;
  u16* v_m_t  = v_m    + 524288;
  u16* head_m = v_m_t  + 524288;
  u16* k_c    = head_m + 524288;
  u16* v_c    = k_c    + 524288;
  u16* v_c_t  = v_c    + 524288;
  u16* q_c    = v_c_t  + 524288;
  u16* head_c = q_c    + 524288;
  u16* mmh    = head_c + 524288;             // 8192*512
  u16* mh     = mmh    + 4194304;            // 8192*512
  u16* xb     = mh     + 4194304;            // 8192*512 bf16 (LN out for FFN)
  float* xf   = (float*)(xb + 4194304);      // 8192*512 fp32 (LN out residual)
  // aliases over dead regions:
  u16* hbuf   = enc_b;                       // 8192*2048, alias enc_b..mmh (dead)
  u16* ffn    = mh;                          // 8192*512, alias mh (dead)

  dim3 b256(256), tb(32,8);

  // output 0: encoder passthrough (fp32 exact)
  copyf_k<<<dim3(4096), b256, 0, stream>>>(enc, out, (long)SEQ*DM/4);

  // fp32 -> bf16 activations
  cvt_k<<<dim3(2048), b256, 0, stream>>>(enc,  enc_b,  (long)SEQ*DM/8);
  cvt_k<<<dim3(2048), b256, 0, stream>>>(prev, prev_b, (long)SEQ*DM/8);

  // weight prep (fp32 in -> transposed bf16 out)
  transpose_k<1><<<dim3(2,16),  tb, 0, stream>>>(wq_m, wq_m_t, DM, HD);
  transpose_k<1><<<dim3(2,16),  tb, 0, stream>>>(wk_m, wk_m_t, DM, HD);
  transpose_k<1><<<dim3(2,16),  tb, 0, stream>>>(wv_m, wv_m_t, DM, HD);
  transpose_k<1><<<dim3(2,16),  tb, 0, stream>>>(wq_c, wq_c_t, DM, HD);
  transpose_k<1><<<dim3(2,16),  tb, 0, stream>>>(wk_c, wk_c_t, DM, HD);
  transpose_k<1><<<dim3(2,16),  tb, 0, stream>>>(wv_c, wv_c_t, DM, HD);
  transpose_k<1><<<dim3(64,16), tb, 0, stream>>>(w1,   w1_t,   DM, HFF);
  transpose_k<1><<<dim3(16,64), tb, 0, stream>>>(w2,   w2_t,   HFF, DM);
  wosum_k<<<dim3(128), b256, 0, stream>>>(w_o, wost);

  // projections: q_m,k_m,v_m = prev @ {wq,wk,wv}_m ; k_c,v_c = enc @ {wk,wv}_c
  gemm_bt<64,64,2,2,0><<<dim3(SEQ/64,1,3), b256, 0, stream>>>(prev_b, wq_m_t, q_m, nullptr, HD, DM, 32768, 524288);
  gemm_bt<64,64,2,2,0><<<dim3(SEQ/64,1,2), b256, 0, stream>>>(enc_b,  wk_c_t, k_c, nullptr, HD, DM, 32768, 524288);
  transpose_k<0><<<dim3(2,256), tb, 0, stream>>>(v_m, v_m_t, SEQ, HD);
  transpose_k<0><<<dim3(2,256), tb, 0, stream>>>(v_c, v_c_t, SEQ, HD);

  // masked self-attention + folded w_o
  attn_k<true><<<dim3(SEQ/64), b256, 0, stream>>>(q_m, k_m, v_m_t, head_m);
  gemm_bt<128,128,2,2,0><<<dim3(SEQ/128,4,1), b256, 0, stream>>>(head_m, wost, mmh, nullptr, DM, HD, 0, 0);

  // cross attention + folded w_o
  gemm_bt<64,64,2,2,0><<<dim3(SEQ/64,1,1), b256, 0, stream>>>(mmh, wq_c_t, q_c, nullptr, HD, DM, 0, 0);
  attn_k<false><<<dim3(SEQ/64), b256, 0, stream>>>(q_c, k_c, v_c_t, head_c);
  gemm_bt<128,128,2,2,0><<<dim3(SEQ/128,4,1), b256, 0, stream>>>(head_c, wost, mh, nullptr, DM, HD, 0, 0);

  // x = LN(mh + prev): fp32 out (residual) + bf16 out (FFN input)
  add_ln<true><<<dim3(SEQ/4), b256, 0, stream>>>(mh, prev, ln_g, ln_b, xf, xb);

  // FFN
  gemm_bt<128,128,2,2,2><<<dim3(SEQ/128,HFF/128,1), b256, 0, stream>>>(xb, w1_t, hbuf, b1, HFF, DM, 0, 0);
  gemm_bt<128,128,2,2,1><<<dim3(SEQ/128,4,1),       b256, 0, stream>>>(hbuf, w2_t, ffn, b2, DM, HFF, 0, 0);

  // out1 = LN(ffn + x), fp32
  add_ln<false><<<dim3(SEQ/4), b256, 0, stream>>>(ffn, xf, ln_g, ln_b, out + (long)SEQ*DM, nullptr);
}

// Round 3
// 302.799 us; speedup vs baseline: 2.0195x; 2.0195x over previous
//
#include <hip/hip_runtime.h>
#include <hip/hip_bf16.h>

typedef unsigned short u16;
typedef __attribute__((ext_vector_type(4))) float f32x4;
typedef __attribute__((ext_vector_type(8))) __bf16 bf16x8;
typedef __attribute__((ext_vector_type(8))) short short8;

constexpr int SEQ = 8192;
constexpr int DM  = 512;
constexpr int HD  = 64;
constexpr int HFF = 2048;

__device__ __forceinline__ float b2f(u16 u){
  union { unsigned int i; float f; } v; v.i = ((unsigned int)u) << 16; return v.f;
}
__device__ __forceinline__ u16 f2b(float f){
  union { float f; unsigned int i; } v; v.f = f;
  unsigned int r = v.i + 0x7FFFu + ((v.i >> 16) & 1u);
  return (u16)(r >> 16);
}

// ------- fused: out0 = enc (fp32 passthrough), enc_b = bf16(enc) ----------
__global__ __launch_bounds__(256) void copycvt_k(const float* __restrict__ in,
                                                 float* __restrict__ outf,
                                                 u16* __restrict__ outb, long n8){
  long i = blockIdx.x * 256L + threadIdx.x;
  if(i >= n8) return;
  f32x4 a = ((const f32x4*)in)[i*2];
  f32x4 b = ((const f32x4*)in)[i*2+1];
  ((f32x4*)outf)[i*2]   = a;
  ((f32x4*)outf)[i*2+1] = b;
  u16 ov[8];
  for(int j=0;j<4;j++){ ov[j] = f2b(a[j]); ov[4+j] = f2b(b[j]); }
  ((short8*)outb)[i] = *(short8*)ov;
}

// ---------------- fp32 -> bf16 convert, 8 elems/thread ----------------
__global__ __launch_bounds__(256) void cvt_k(const float* __restrict__ in,
                                             u16* __restrict__ out, long n8){
  long i = blockIdx.x * 256L + threadIdx.x;
  if(i >= n8) return;
  f32x4 a = ((const f32x4*)in)[i*2];
  f32x4 b = ((const f32x4*)in)[i*2+1];
  u16 ov[8];
  for(int j=0;j<4;j++){ ov[j] = f2b(a[j]); ov[4+j] = f2b(b[j]); }
  ((short8*)out)[i] = *(short8*)ov;
}

// ---------------- 32x32 transpose; IN_F: 1=fp32 input, 0=bf16 input ------
template<int IN_F>
__global__ __launch_bounds__(256) void transpose_k(const void* __restrict__ inp,
                                                   u16* __restrict__ out, int R, int C){
  __shared__ u16 t[32][33];
  int c0 = blockIdx.x*32, r0 = blockIdx.y*32;
  int tx = threadIdx.x, ty = threadIdx.y;     // blockDim (32,8)
  for(int i=0;i<4;i++){
    long idx = (long)(r0+ty+i*8)*C + c0+tx;
    u16 v;
    if constexpr (IN_F) v = f2b(((const float*)inp)[idx]);
    else                v = ((const u16*)inp)[idx];
    t[ty+i*8][tx] = v;
  }
  __syncthreads();
  for(int i=0;i<4;i++) out[(long)(c0+ty+i*8)*R + r0+tx] = t[tx][ty+i*8];
}

// ---------------- w_o head-sum, transposed: outT[n*64+p] = sum_h wo[h*64+p][n]
__global__ __launch_bounds__(256) void wosum_k(const float* __restrict__ wo,
                                               u16* __restrict__ outT){
  int tid = blockIdx.x*256 + threadIdx.x;     // 32768 total
  int n = tid >> 6, p = tid & 63;
  float s = 0.f;
  for(int h=0; h<8; h++) s += wo[(long)(h*64+p)*DM + n];
  outT[n*64+p] = f2b(s);
}

// ---------------- fused residual-add + LayerNorm (row=512, 1 wave/row) ----
template<bool WRITE_BF>
__global__ __launch_bounds__(256) void add_ln(const u16* __restrict__ Xa,
                                              const float* __restrict__ Xb,
                                              const float* __restrict__ G,
                                              const float* __restrict__ Bb,
                                              float* __restrict__ OutF,
                                              u16* __restrict__ OutB){
  int row  = blockIdx.x*4 + (threadIdx.x>>6);
  int lane = threadIdx.x & 63;
  short8 a8 = *(const short8*)&Xa[(long)row*DM + lane*8];
  f32x4 b0 = *(const f32x4*)&Xb[(long)row*DM + lane*8];
  f32x4 b1 = *(const f32x4*)&Xb[(long)row*DM + lane*8 + 4];
  float x[8]; float s=0.f, s2=0.f;
  for(int i=0;i<8;i++){
    float bv = (i<4) ? b0[i] : b1[i-4];
    x[i] = b2f((u16)a8[i]) + bv;
    s += x[i]; s2 += x[i]*x[i];
  }
  for(int o=1;o<64;o<<=1){ s += __shfl_xor(s,o); s2 += __shfl_xor(s2,o); }
  float mu  = s * (1.f/DM);
  float var = s2 * (1.f/DM) - mu*mu;
  float rstd = rsqrtf(var + 1e-5f);
  f32x4 g0 = *(const f32x4*)&G[lane*8];
  f32x4 g1 = *(const f32x4*)&G[lane*8+4];
  f32x4 p0 = *(const f32x4*)&Bb[lane*8];
  f32x4 p1 = *(const f32x4*)&Bb[lane*8+4];
  float of[8]; u16 ob[8];
  for(int i=0;i<8;i++){
    float gv = (i<4)?g0[i]:g1[i-4], bv2 = (i<4)?p0[i]:p1[i-4];
    float v = (x[i]-mu)*rstd*gv + bv2;
    of[i] = v; ob[i] = f2b(v);
  }
  *(f32x4*)&OutF[(long)row*DM + lane*8]     = *(f32x4*)&of[0];
  *(f32x4*)&OutF[(long)row*DM + lane*8 + 4] = *(f32x4*)&of[4];
  if constexpr (WRITE_BF)
    *(short8*)&OutB[(long)row*DM + lane*8] = *(short8*)ob;
}

// ---------------- generic bf16 GEMM: C[M,N] = epi(A[M,K] @ Bt[N,K]^T + bias)
template<int BM,int BN,int WR,int WC,int EPI>
__global__ __launch_bounds__(256) void gemm_bt(const u16* __restrict__ A,
                                               const u16* __restrict__ Bt,
                                               u16* __restrict__ C,
                                               const float* __restrict__ bias,
                                               int N, int K, long sB, long sC){
  constexpr int WM = BM/WR, WN = BN/WC;
  constexpr int MF = WM/16, NF = WN/16;
  constexpr int LDK = 72;                       // 64 + 8 pad
  __shared__ u16 As[BM*LDK];
  __shared__ u16 Bs[BN*LDK];

  const int tid = threadIdx.x;
  const int wid = tid >> 6, lane = tid & 63;
  const int g = lane >> 4, lr = lane & 15;
  const int m0 = blockIdx.x * BM;
  const int n0 = blockIdx.y * BN;
  Bt += (long)blockIdx.z * sB;
  C  += (long)blockIdx.z * sC;
  const int wr = wid / WC, wc = wid % WC;

  f32x4 acc[MF][NF];
  for(int m=0;m<MF;m++) for(int n=0;n<NF;n++) acc[m][n] = (f32x4)0.f;

  for(int k0=0; k0<K; k0+=64){
    for(int it=0; it<BM*8/256; ++it){
      int idx = tid + it*256; int r = idx>>3, c8 = idx&7;
      *(short8*)&As[r*LDK + c8*8] = *(const short8*)&A[(long)(m0+r)*K + k0 + c8*8];
    }
    for(int it=0; it<BN*8/256; ++it){
      int idx = tid + it*256; int r = idx>>3, c8 = idx&7;
      *(short8*)&Bs[r*LDK + c8*8] = *(const short8*)&Bt[(long)(n0+r)*K + k0 + c8*8];
    }
    __syncthreads();
    for(int kc=0;kc<2;kc++){
      bf16x8 af[MF], bfr[NF];
      for(int m=0;m<MF;m++) af[m]  = *(const bf16x8*)&As[(wr*WM + m*16 + lr)*LDK + kc*32 + g*8];
      for(int n=0;n<NF;n++) bfr[n] = *(const bf16x8*)&Bs[(wc*WN + n*16 + lr)*LDK + kc*32 + g*8];
      for(int m=0;m<MF;m++)
        for(int n=0;n<NF;n++)
          acc[m][n] = __builtin_amdgcn_mfma_f32_16x16x32_bf16(af[m], bfr[n], acc[m][n], 0,0,0);
    }
    __syncthreads();
  }
  for(int m=0;m<MF;m++){
    int row = m0 + wr*WM + m*16 + g*4;
    for(int n=0;n<NF;n++){
      int col = n0 + wc*WN + n*16 + lr;
      float bv = 0.f;
      if constexpr (EPI>=1) bv = bias[col];
      for(int j=0;j<4;j++){
        float v = acc[m][n][j] + bv;
        if constexpr (EPI==2) v = (v >= 0.f) ? v : 0.01f*v;
        C[(long)(row+j)*N + col] = f2b(v);
      }
    }
  }
}

// ------------- flash attention PARTIAL: (Q-tile 64) x (KV-chunk 1024) -----
// Writes raw O (un-normalized, fp32) + per-row (m,l). grid (SEQ/64, 8).
template<bool CAUSAL>
__global__ __launch_bounds__(256) void attn_part_k(const u16* __restrict__ Q,
                                                   const u16* __restrict__ Km,
                                                   const u16* __restrict__ Vt,
                                                   float* __restrict__ Op,
                                                   float* __restrict__ Ml){
  constexpr int LDK = 72;
  constexpr int NCH = 8;
  __shared__ u16 Ks[64*LDK];      // [kv][d]
  __shared__ u16 Vs[64*LDK];      // [d][kv]
  __shared__ u16 Ps[4*16*LDK];    // per-wave P tile [16][64] (wave-private)

  const int qb = blockIdx.x, ci = blockIdx.y;
  if(CAUSAL && ci*16 > qb) return;          // fully-masked chunk

  const int tid = threadIdx.x, wid = tid>>6, lane = tid&63;
  const int g = lane>>4, lr = lane&15;
  const int qrow = qb*64 + wid*16;

  bf16x8 qf[2];
  for(int kc=0;kc<2;kc++)
    qf[kc] = *(const bf16x8*)&Q[(long)(qrow + lr)*HD + kc*32 + g*8];

  f32x4 o[4]; for(int n=0;n<4;n++) o[n] = (f32x4)0.f;
  float mst[4], lst[4];
  for(int j=0;j<4;j++){ mst[j] = -INFINITY; lst[j] = 0.f; }

  const int tmax = CAUSAL ? min(16, qb - ci*16 + 1) : 16;
  for(int t=0; t<tmax; ++t){
    const int kv0 = ci*1024 + t*64;
    __syncthreads();                       // prev iter done with Ks/Vs
    for(int it=0; it<2; ++it){
      int idx = tid + it*256; int r = idx>>3, c8 = idx&7;
      *(short8*)&Ks[r*LDK + c8*8] = *(const short8*)&Km[(long)(kv0+r)*HD + c8*8];
      *(short8*)&Vs[r*LDK + c8*8] = *(const short8*)&Vt[(long)r*SEQ + kv0 + c8*8];
    }
    __syncthreads();

    f32x4 s[4]; for(int n=0;n<4;n++) s[n] = (f32x4)0.f;
    for(int kc=0;kc<2;kc++){
      for(int n=0;n<4;n++){
        bf16x8 kf = *(const bf16x8*)&Ks[(n*16+lr)*LDK + kc*32 + g*8];
        s[n] = __builtin_amdgcn_mfma_f32_16x16x32_bf16(qf[kc], kf, s[n], 0,0,0);
      }
    }
    for(int n=0;n<4;n++)
      for(int j=0;j<4;j++){
        float v = s[n][j]*0.125f;
        if(CAUSAL){
          int col = kv0 + n*16 + lr, row = qrow + g*4 + j;
          if(col > row) v = -INFINITY;
        }
        s[n][j] = v;
      }
    float fac[4], rs[4];
    for(int j=0;j<4;j++){
      float v = fmaxf(fmaxf(s[0][j],s[1][j]), fmaxf(s[2][j],s[3][j]));
      v = fmaxf(v, __shfl_xor(v,1)); v = fmaxf(v, __shfl_xor(v,2));
      v = fmaxf(v, __shfl_xor(v,4)); v = fmaxf(v, __shfl_xor(v,8));
      float mn = fmaxf(mst[j], v);
      fac[j] = __expf(mst[j] - mn);
      mst[j] = mn;
      rs[j] = 0.f;
    }
    for(int n=0;n<4;n++)
      for(int j=0;j<4;j++){
        float p = __expf(s[n][j] - mst[j]);
        rs[j] += p;
        Ps[(wid*16 + g*4 + j)*LDK + n*16 + lr] = f2b(p);
      }
    for(int j=0;j<4;j++){
      float v = rs[j];
      v += __shfl_xor(v,1); v += __shfl_xor(v,2);
      v += __shfl_xor(v,4); v += __shfl_xor(v,8);
      lst[j] = lst[j]*fac[j] + v;
    }
    for(int n=0;n<4;n++)
      for(int j=0;j<4;j++) o[n][j] *= fac[j];
    // Ps is wave-private: no barrier needed before PV
    for(int kc=0;kc<2;kc++){
      bf16x8 pf = *(const bf16x8*)&Ps[(wid*16 + lr)*LDK + kc*32 + g*8];
      for(int n=0;n<4;n++){
        bf16x8 vf = *(const bf16x8*)&Vs[(n*16+lr)*LDK + kc*32 + g*8];
        o[n] = __builtin_amdgcn_mfma_f32_16x16x32_bf16(pf, vf, o[n], 0,0,0);
      }
    }
  }
  const long pr = (long)(qb*NCH + ci)*64;
  for(int n=0;n<4;n++)
    for(int j=0;j<4;j++)
      Op[(pr + wid*16 + g*4 + j)*64 + n*16 + lr] = o[n][j];
  if(lr == 0)
    for(int j=0;j<4;j++){
      Ml[(pr + wid*16 + g*4 + j)*2]     = mst[j];
      Ml[(pr + wid*16 + g*4 + j)*2 + 1] = lst[j];
    }
}

// ------------- flash attention REDUCE: merge chunk partials per row -------
template<bool CAUSAL>
__global__ __launch_bounds__(256) void attn_red_k(const float* __restrict__ Op,
                                                  const float* __restrict__ Ml,
                                                  u16* __restrict__ O){
  int r = blockIdx.x*4 + (threadIdx.x>>6);
  int d = threadIdx.x & 63;
  int qb = r >> 6, rt = r & 63;
  int nch = CAUSAL ? (qb>>4) + 1 : 8;
  long base = (long)qb*8*64 + rt;
  float m = -INFINITY;
  for(int i=0;i<nch;i++) m = fmaxf(m, Ml[(base + i*64)*2]);
  float L = 0.f, acc = 0.f;
  for(int i=0;i<nch;i++){
    float mi = Ml[(base + i*64)*2], li = Ml[(base + i*64)*2 + 1];
    float w = __expf(mi - m);
    L   += li * w;
    acc += w * Op[(base + i*64)*64 + d];
  }
  O[(long)r*HD + d] = f2b(acc / L);
}

extern "C" void kernel_launch(void* const* d_in, const int* in_sizes, int n_in,
                              void* d_out, int out_size, void* d_ws, size_t ws_size,
                              hipStream_t stream){
  const float* enc  = (const float*)d_in[0];
  const float* prev = (const float*)d_in[1];
  const float* wq_m = (const float*)d_in[2];
  const float* wk_m = (const float*)d_in[3];
  const float* wv_m = (const float*)d_in[4];
  const float* wq_c = (const float*)d_in[5];
  const float* wk_c = (const float*)d_in[6];
  const float* wv_c = (const float*)d_in[7];
  const float* w_o  = (const float*)d_in[8];
  const float* ln_g = (const float*)d_in[9];
  const float* ln_b = (const float*)d_in[10];
  const float* w1   = (const float*)d_in[11];
  const float* b1   = (const float*)d_in[12];
  const float* w2   = (const float*)d_in[13];
  const float* b2   = (const float*)d_in[14];
  float* out = (float*)d_out;
  u16* ws  = (u16*)d_ws;

  // workspace layout (u16 element offsets) — total ≈ 74 MB (proven fit)
  u16* wq_m_t = ws;
  u16* wk_m_t = wq_m_t + 32768;
  u16* wv_m_t = wk_m_t + 32768;
  u16* wq_c_t = wv_m_t + 32768;
  u16* wk_c_t = wq_c_t + 32768;
  u16* wv_c_t = wk_c_t + 32768;
  u16* wost   = wv_c_t + 32768;              // 512*64
  u16* w1_t   = wost   + 32768;              // 2048*512
  u16* w2_t   = w1_t   + 1048576;            // 512*2048
  u16* enc_b  = w2_t   + 1048576;            // 8192*512 bf16
  u16* prev_b = enc_b  + 4194304;
  u16* q_m    = prev_b + 4194304;            // 8192*64 each
  u16* k_m    = q_m    + 524288;
  u16* v_m    = k_m    + 524288;
  u16* v_m_t  = v_m    + 524288;
  u16* head_m = v_m_t  + 524288;
  u16* k_c    = head_m + 524288;
  u16* v_c    = k_c    + 524288;
  u16* v_c_t  = v_c    + 524288;
  u16* q_c    = v_c_t  + 524288;
  u16* head_c = q_c    + 524288;
  u16* mmh    = head_c + 524288;             // 8192*512
  u16* mh     = mmh    + 4194304;            // 8192*512
  u16* xb     = mh     + 4194304;            // 8192*512 bf16 (LN out for FFN)
  float* xf   = (float*)(xb + 4194304);      // 8192*512 fp32 (LN out residual)
  // aliases over dead/not-yet-live regions:
  u16* hbuf   = enc_b;                       // 8192*2048 bf16 (FFN mid), enc_b dead by then
  u16* ffn    = mh;                          // 8192*512, mh dead by then
  float* Op   = (float*)xb;                  // 128*8*64*64 fp32 = 8.4M u16, xb/xf live only after attn
  float* Ml   = Op + 128*8*64*64;            // 128*8*64*2 fp32

  dim3 b256(256), tb(32,8);

  // output 0 passthrough + enc bf16 convert (fused)
  copycvt_k<<<dim3(2048), b256, 0, stream>>>(enc, out, enc_b, (long)SEQ*DM/8);
  cvt_k<<<dim3(2048), b256, 0, stream>>>(prev, prev_b, (long)SEQ*DM/8);

  // weight prep (fp32 in -> transposed bf16 out)
  transpose_k<1><<<dim3(2,16),  tb, 0, stream>>>(wq_m, wq_m_t, DM, HD);
  transpose_k<1><<<dim3(2,16),  tb, 0, stream>>>(wk_m, wk_m_t, DM, HD);
  transpose_k<1><<<dim3(2,16),  tb, 0, stream>>>(wv_m, wv_m_t, DM, HD);
  transpose_k<1><<<dim3(2,16),  tb, 0, stream>>>(wq_c, wq_c_t, DM, HD);
  transpose_k<1><<<dim3(2,16),  tb, 0, stream>>>(wk_c, wk_c_t, DM, HD);
  transpose_k<1><<<dim3(2,16),  tb, 0, stream>>>(wv_c, wv_c_t, DM, HD);
  transpose_k<1><<<dim3(64,16), tb, 0, stream>>>(w1,   w1_t,   DM, HFF);
  transpose_k<1><<<dim3(16,64), tb, 0, stream>>>(w2,   w2_t,   HFF, DM);
  wosum_k<<<dim3(128), b256, 0, stream>>>(w_o, wost);

  // projections
  gemm_bt<64,64,2,2,0><<<dim3(SEQ/64,1,3), b256, 0, stream>>>(prev_b, wq_m_t, q_m, nullptr, HD, DM, 32768, 524288);
  gemm_bt<64,64,2,2,0><<<dim3(SEQ/64,1,2), b256, 0, stream>>>(enc_b,  wk_c_t, k_c, nullptr, HD, DM, 32768, 524288);
  transpose_k<0><<<dim3(2,256), tb, 0, stream>>>(v_m, v_m_t, SEQ, HD);
  transpose_k<0><<<dim3(2,256), tb, 0, stream>>>(v_c, v_c_t, SEQ, HD);

  // masked self-attention (KV-split) + folded w_o
  attn_part_k<true><<<dim3(SEQ/64, 8), b256, 0, stream>>>(q_m, k_m, v_m_t, Op, Ml);
  attn_red_k<true><<<dim3(SEQ/4), b256, 0, stream>>>(Op, Ml, head_m);
  gemm_bt<128,128,2,2,0><<<dim3(SEQ/128,4,1), b256, 0, stream>>>(head_m, wost, mmh, nullptr, DM, HD, 0, 0);

  // cross attention (KV-split) + folded w_o
  gemm_bt<64,64,2,2,0><<<dim3(SEQ/64,1,1), b256, 0, stream>>>(mmh, wq_c_t, q_c, nullptr, HD, DM, 0, 0);
  attn_part_k<false><<<dim3(SEQ/64, 8), b256, 0, stream>>>(q_c, k_c, v_c_t, Op, Ml);
  attn_red_k<false><<<dim3(SEQ/4), b256, 0, stream>>>(Op, Ml, head_c);
  gemm_bt<128,128,2,2,0><<<dim3(SEQ/128,4,1), b256, 0, stream>>>(head_c, wost, mh, nullptr, DM, HD, 0, 0);

  // x = LN(mh + prev): fp32 out (residual) + bf16 out (FFN input)
  add_ln<true><<<dim3(SEQ/4), b256, 0, stream>>>(mh, prev, ln_g, ln_b, xf, xb);

  // FFN
  gemm_bt<128,128,2,2,2><<<dim3(SEQ/128,HFF/128,1), b256, 0, stream>>>(xb, w1_t, hbuf, b1, HFF, DM, 0, 0);
  gemm_bt<128,128,2,2,1><<<dim3(SEQ/128,4,1),       b256, 0, stream>>>(hbuf, w2_t, ffn, b2, DM, HFF, 0, 0);

  // out1 = LN(ffn + x), fp32
  add_ln<false><<<dim3(SEQ/4), b256, 0, stream>>>(ffn, xf, ln_g, ln_b, out + (long)SEQ*DM, nullptr);
}

// Round 5
// 286.283 us; speedup vs baseline: 2.1360x; 1.0577x over previous
//
#include <hip/hip_runtime.h>
#include <hip/hip_bf16.h>

typedef unsigned short u16;
typedef __attribute__((ext_vector_type(4))) float f32x4;
typedef __attribute__((ext_vector_type(8))) __bf16 bf16x8;
typedef __attribute__((ext_vector_type(8))) short short8;
typedef __attribute__((ext_vector_type(4))) short s16x4;

constexpr int SEQ = 8192;
constexpr int DM  = 512;
constexpr int HD  = 64;
constexpr int HFF = 2048;

__device__ __forceinline__ float b2f(u16 u){
  union { unsigned int i; float f; } v; v.i = ((unsigned int)u) << 16; return v.f;
}
__device__ __forceinline__ u16 f2b(float f){
  union { float f; unsigned int i; } v; v.f = f;
  unsigned int r = v.i + 0x7FFFu + ((v.i >> 16) & 1u);
  return (u16)(r >> 16);
}

// ------- fused: out0 = enc (fp32 passthrough), enc_b = bf16(enc) ----------
__global__ __launch_bounds__(256) void copycvt_k(const float* __restrict__ in,
                                                 float* __restrict__ outf,
                                                 u16* __restrict__ outb, long n8){
  long i = blockIdx.x * 256L + threadIdx.x;
  if(i >= n8) return;
  f32x4 a = ((const f32x4*)in)[i*2];
  f32x4 b = ((const f32x4*)in)[i*2+1];
  ((f32x4*)outf)[i*2]   = a;
  ((f32x4*)outf)[i*2+1] = b;
  u16 ov[8];
  for(int j=0;j<4;j++){ ov[j] = f2b(a[j]); ov[4+j] = f2b(b[j]); }
  ((short8*)outb)[i] = *(short8*)ov;
}

__global__ __launch_bounds__(256) void cvt_k(const float* __restrict__ in,
                                             u16* __restrict__ out, long n8){
  long i = blockIdx.x * 256L + threadIdx.x;
  if(i >= n8) return;
  f32x4 a = ((const f32x4*)in)[i*2];
  f32x4 b = ((const f32x4*)in)[i*2+1];
  u16 ov[8];
  for(int j=0;j<4;j++){ ov[j] = f2b(a[j]); ov[4+j] = f2b(b[j]); }
  ((short8*)out)[i] = *(short8*)ov;
}

// ------- batched transpose of the six [512,64] projection weights --------
__global__ __launch_bounds__(256) void wtrans6_k(const float* __restrict__ w0,
                                                 const float* __restrict__ w1,
                                                 const float* __restrict__ w2,
                                                 const float* __restrict__ w3,
                                                 const float* __restrict__ w4,
                                                 const float* __restrict__ w5,
                                                 u16* __restrict__ out){
  __shared__ u16 t[32][33];
  const float* ins[6] = {w0,w1,w2,w3,w4,w5};
  const float* in = ins[blockIdx.z];
  u16* o = out + (long)blockIdx.z * 32768;
  int c0 = blockIdx.x*32, r0 = blockIdx.y*32;
  int tx = threadIdx.x, ty = threadIdx.y;     // blockDim (32,8)
  for(int i=0;i<4;i++)
    t[ty+i*8][tx] = f2b(in[(long)(r0+ty+i*8)*HD + c0+tx]);
  __syncthreads();
  for(int i=0;i<4;i++) o[(long)(c0+ty+i*8)*DM + r0+tx] = t[tx][ty+i*8];
}

// ---------------- generic 32x32 transpose; IN_F: 1=fp32 in, 0=bf16 in ----
template<int IN_F>
__global__ __launch_bounds__(256) void transpose_k(const void* __restrict__ inp,
                                                   u16* __restrict__ out, int R, int C){
  __shared__ u16 t[32][33];
  int c0 = blockIdx.x*32, r0 = blockIdx.y*32;
  int tx = threadIdx.x, ty = threadIdx.y;     // blockDim (32,8)
  for(int i=0;i<4;i++){
    long idx = (long)(r0+ty+i*8)*C + c0+tx;
    u16 v;
    if constexpr (IN_F) v = f2b(((const float*)inp)[idx]);
    else                v = ((const u16*)inp)[idx];
    t[ty+i*8][tx] = v;
  }
  __syncthreads();
  for(int i=0;i<4;i++) out[(long)(c0+ty+i*8)*R + r0+tx] = t[tx][ty+i*8];
}

// ------- batched transpose of two [8192,64] V matrices -> [64,8192] ------
__global__ __launch_bounds__(256) void vtrans2_k(const u16* __restrict__ v0,
                                                 u16* __restrict__ o0,
                                                 const u16* __restrict__ v1,
                                                 u16* __restrict__ o1){
  __shared__ u16 t[32][33];
  const u16* in = blockIdx.z ? v1 : v0;
  u16* o = blockIdx.z ? o1 : o0;
  int c0 = blockIdx.x*32, r0 = blockIdx.y*32;
  int tx = threadIdx.x, ty = threadIdx.y;
  for(int i=0;i<4;i++) t[ty+i*8][tx] = in[(long)(r0+ty+i*8)*HD + c0+tx];
  __syncthreads();
  for(int i=0;i<4;i++) o[(long)(c0+ty+i*8)*SEQ + r0+tx] = t[tx][ty+i*8];
}

// ---------------- w_o head-sum, transposed ----------------
__global__ __launch_bounds__(256) void wosum_k(const float* __restrict__ wo,
                                               u16* __restrict__ outT){
  int tid = blockIdx.x*256 + threadIdx.x;     // 32768 total
  int n = tid >> 6, p = tid & 63;
  float s = 0.f;
  for(int h=0; h<8; h++) s += wo[(long)(h*64+p)*DM + n];
  outT[n*64+p] = f2b(s);
}

// ---------------- fused residual-add + LayerNorm ----------------
template<bool WRITE_BF>
__global__ __launch_bounds__(256) void add_ln(const u16* __restrict__ Xa,
                                              const float* __restrict__ Xb,
                                              const float* __restrict__ G,
                                              const float* __restrict__ Bb,
                                              float* __restrict__ OutF,
                                              u16* __restrict__ OutB){
  int row  = blockIdx.x*4 + (threadIdx.x>>6);
  int lane = threadIdx.x & 63;
  short8 a8 = *(const short8*)&Xa[(long)row*DM + lane*8];
  f32x4 b0 = *(const f32x4*)&Xb[(long)row*DM + lane*8];
  f32x4 b1 = *(const f32x4*)&Xb[(long)row*DM + lane*8 + 4];
  float x[8]; float s=0.f, s2=0.f;
  for(int i=0;i<8;i++){
    float bv = (i<4) ? b0[i] : b1[i-4];
    x[i] = b2f((u16)a8[i]) + bv;
    s += x[i]; s2 += x[i]*x[i];
  }
  for(int o=1;o<64;o<<=1){ s += __shfl_xor(s,o); s2 += __shfl_xor(s2,o); }
  float mu  = s * (1.f/DM);
  float var = s2 * (1.f/DM) - mu*mu;
  float rstd = rsqrtf(var + 1e-5f);
  f32x4 g0 = *(const f32x4*)&G[lane*8];
  f32x4 g1 = *(const f32x4*)&G[lane*8+4];
  f32x4 p0 = *(const f32x4*)&Bb[lane*8];
  f32x4 p1 = *(const f32x4*)&Bb[lane*8+4];
  float of[8]; u16 ob[8];
  for(int i=0;i<8;i++){
    float gv = (i<4)?g0[i]:g1[i-4], bv2 = (i<4)?p0[i]:p1[i-4];
    float v = (x[i]-mu)*rstd*gv + bv2;
    of[i] = v; ob[i] = f2b(v);
  }
  *(f32x4*)&OutF[(long)row*DM + lane*8]     = *(f32x4*)&of[0];
  *(f32x4*)&OutF[(long)row*DM + lane*8 + 4] = *(f32x4*)&of[4];
  if constexpr (WRITE_BF)
    *(short8*)&OutB[(long)row*DM + lane*8] = *(short8*)ob;
}

// ---------------- generic bf16 GEMM: C[M,N] = epi(A[M,K] @ Bt[N,K]^T + bias)
template<int BM,int BN,int WR,int WC,int EPI>
__global__ __launch_bounds__(256) void gemm_bt(const u16* __restrict__ A,
                                               const u16* __restrict__ Bt,
                                               u16* __restrict__ C,
                                               const float* __restrict__ bias,
                                               int N, int K, long sB, long sC){
  constexpr int WM = BM/WR, WN = BN/WC;
  constexpr int MF = WM/16, NF = WN/16;
  constexpr int LDK = 72;                       // 64 + 8 pad
  __shared__ u16 As[BM*LDK];
  __shared__ u16 Bs[BN*LDK];

  const int tid = threadIdx.x;
  const int wid = tid >> 6, lane = tid & 63;
  const int g = lane >> 4, lr = lane & 15;
  const int m0 = blockIdx.x * BM;
  const int n0 = blockIdx.y * BN;
  Bt += (long)blockIdx.z * sB;
  C  += (long)blockIdx.z * sC;
  const int wr = wid / WC, wc = wid % WC;

  f32x4 acc[MF][NF];
  for(int m=0;m<MF;m++) for(int n=0;n<NF;n++) acc[m][n] = (f32x4)0.f;

  for(int k0=0; k0<K; k0+=64){
    for(int it=0; it<BM*8/256; ++it){
      int idx = tid + it*256; int r = idx>>3, c8 = idx&7;
      *(short8*)&As[r*LDK + c8*8] = *(const short8*)&A[(long)(m0+r)*K + k0 + c8*8];
    }
    for(int it=0; it<BN*8/256; ++it){
      int idx = tid + it*256; int r = idx>>3, c8 = idx&7;
      *(short8*)&Bs[r*LDK + c8*8] = *(const short8*)&Bt[(long)(n0+r)*K + k0 + c8*8];
    }
    __syncthreads();
    for(int kc=0;kc<2;kc++){
      bf16x8 af[MF], bfr[NF];
      for(int m=0;m<MF;m++) af[m]  = *(const bf16x8*)&As[(wr*WM + m*16 + lr)*LDK + kc*32 + g*8];
      for(int n=0;n<NF;n++) bfr[n] = *(const bf16x8*)&Bs[(wc*WN + n*16 + lr)*LDK + kc*32 + g*8];
      for(int m=0;m<MF;m++)
        for(int n=0;n<NF;n++)
          acc[m][n] = __builtin_amdgcn_mfma_f32_16x16x32_bf16(af[m], bfr[n], acc[m][n], 0,0,0);
    }
    __syncthreads();
  }
  for(int m=0;m<MF;m++){
    int row = m0 + wr*WM + m*16 + g*4;
    for(int n=0;n<NF;n++){
      int col = n0 + wc*WN + n*16 + lr;
      float bv = 0.f;
      if constexpr (EPI>=1) bv = bias[col];
      for(int j=0;j<4;j++){
        float v = acc[m][n][j] + bv;
        if constexpr (EPI==2) v = (v >= 0.f) ? v : 0.01f*v;
        C[(long)(row+j)*N + col] = f2b(v);
      }
    }
  }
}

// ------------- flash attention PARTIAL: (Q-tile 64) x (KV-chunk 512) -----
// Swapped QK^T (scores lane-local per q-row), exp2 domain, defer-max.
// Writes raw O (fp32) + per-row (m,l) in log2 domain. grid (SEQ/64, 16).
template<bool CAUSAL>
__global__ __launch_bounds__(256) void attn_part_k(const u16* __restrict__ Q,
                                                   const u16* __restrict__ Km,
                                                   const u16* __restrict__ Vt,
                                                   float* __restrict__ Op,
                                                   float* __restrict__ Ml){
  constexpr int LDK = 72;
  constexpr int NCH = 16;    // chunks of 512
  constexpr int CTI = 8;     // 64-wide tiles per chunk
  __shared__ u16 Ks[64*LDK];      // [kv][d]
  __shared__ u16 Vs[64*LDK];      // [d][kv]  (V^T)
  __shared__ u16 Ps[4*16*LDK];    // per-wave P tile [16 q][64 kv]

  const int qb = blockIdx.x, ci = blockIdx.y;
  if(CAUSAL && ci*CTI > qb) return;

  const int tid = threadIdx.x, wid = tid>>6, lane = tid&63;
  const int g = lane>>4, lr = lane&15, r4 = g*4;
  const int qrow = qb*64 + wid*16;

  // Q fragments pre-scaled into exp2 domain: * (1/8) * log2(e)
  bf16x8 qf[2];
  for(int kc=0;kc<2;kc++){
    bf16x8 t = *(const bf16x8*)&Q[(long)(qrow + lr)*HD + kc*32 + g*8];
    for(int i=0;i<8;i++) t[i] = (__bf16)((float)t[i] * 0.1803368801f);
    qf[kc] = t;
  }

  f32x4 o[4]; for(int n=0;n<4;n++) o[n] = (f32x4)0.f;
  float mst = -1e30f, lst = 0.f;

  const int tdiag = qb - ci*CTI;             // diagonal tile idx (may be >= CTI)
  const int tmax = CAUSAL ? min(CTI, tdiag + 1) : CTI;

  // staging registers (T14 async-stage: load t+1 under compute of t)
  const int sr0 = tid>>3, sc0 = (tid&7)*8;
  short8 rK0, rK1, rV0, rV1;
  {
    const int kv0 = ci*512;
    rK0 = *(const short8*)&Km[(long)(kv0+sr0)*HD + sc0];
    rK1 = *(const short8*)&Km[(long)(kv0+sr0+32)*HD + sc0];
    rV0 = *(const short8*)&Vt[(long)sr0*SEQ + kv0 + sc0];
    rV1 = *(const short8*)&Vt[(long)(sr0+32)*SEQ + kv0 + sc0];
  }

  for(int t=0; t<tmax; ++t){
    const int kv0 = ci*512 + t*64;
    __syncthreads();                       // prev-iter consumers done
    *(short8*)&Ks[sr0*LDK + sc0]      = rK0;
    *(short8*)&Ks[(sr0+32)*LDK + sc0] = rK1;
    *(short8*)&Vs[sr0*LDK + sc0]      = rV0;
    *(short8*)&Vs[(sr0+32)*LDK + sc0] = rV1;
    __syncthreads();                       // tile ready
    if(t+1 < tmax){
      const int kn = kv0 + 64;
      rK0 = *(const short8*)&Km[(long)(kn+sr0)*HD + sc0];
      rK1 = *(const short8*)&Km[(long)(kn+sr0+32)*HD + sc0];
      rV0 = *(const short8*)&Vt[(long)sr0*SEQ + kn + sc0];
      rV1 = *(const short8*)&Vt[(long)(sr0+32)*SEQ + kn + sc0];
    }

    // swapped QK^T: s[n][j] = S[q = lr][kv = n*16 + r4 + j]  (log2 domain)
    f32x4 s[4]; for(int n=0;n<4;n++) s[n] = (f32x4)0.f;
    for(int kc=0;kc<2;kc++){
      for(int n=0;n<4;n++){
        bf16x8 kf = *(const bf16x8*)&Ks[(n*16+lr)*LDK + kc*32 + g*8];
        s[n] = __builtin_amdgcn_mfma_f32_16x16x32_bf16(kf, qf[kc], s[n], 0,0,0);
      }
    }
    if(CAUSAL && t == tdiag){
      int row = qrow + lr;
      for(int n=0;n<4;n++)
        for(int j=0;j<4;j++)
          if(kv0 + n*16 + r4 + j > row) s[n][j] = -1e30f;
    }
    // row max (lane-local + 2 shuffles across g-duplicates)
    float pmax = s[0][0];
    for(int n=0;n<4;n++)
      for(int j=0;j<4;j++) pmax = fmaxf(pmax, s[n][j]);
    pmax = fmaxf(pmax, __shfl_xor(pmax,16));
    pmax = fmaxf(pmax, __shfl_xor(pmax,32));
    // defer-max (T13): rescale only when max grew past threshold
    if(__any(pmax > mst + 8.f)){
      float mn = fmaxf(mst, pmax);
      float fac = exp2f(mst - mn);
      mst = mn; lst *= fac;
      float fj0 = __shfl(fac, r4+0), fj1 = __shfl(fac, r4+1);
      float fj2 = __shfl(fac, r4+2), fj3 = __shfl(fac, r4+3);
      for(int n=0;n<4;n++){
        o[n][0] *= fj0; o[n][1] *= fj1; o[n][2] *= fj2; o[n][3] *= fj3;
      }
    }
    // P = exp2(s - m); packed b64 writes (4 consecutive u16 per lane)
    float rs = 0.f;
    for(int n=0;n<4;n++){
      u16 w[4];
      for(int j=0;j<4;j++){
        float p = exp2f(s[n][j] - mst);
        rs += p;
        __bf16 pb = (__bf16)p;
        union { __bf16 b; u16 u; } cv; cv.b = pb;
        w[j] = cv.u;
      }
      *(s16x4*)&Ps[(wid*16 + lr)*LDK + n*16 + r4] = *(s16x4*)w;
    }
    rs += __shfl_xor(rs,16); rs += __shfl_xor(rs,32);
    lst += rs;
    // PV (Ps rows are written/read by same-lr lanes of this wave only)
    for(int kc=0;kc<2;kc++){
      bf16x8 pf = *(const bf16x8*)&Ps[(wid*16 + lr)*LDK + kc*32 + g*8];
      for(int n=0;n<4;n++){
        bf16x8 vf = *(const bf16x8*)&Vs[(n*16+lr)*LDK + kc*32 + g*8];
        o[n] = __builtin_amdgcn_mfma_f32_16x16x32_bf16(pf, vf, o[n], 0,0,0);
      }
    }
  }
  const long pr = (long)(qb*NCH + ci)*64;
  for(int n=0;n<4;n++)
    for(int j=0;j<4;j++)
      Op[(pr + wid*16 + r4 + j)*64 + n*16 + lr] = o[n][j];
  if(lane < 16){
    Ml[(pr + wid*16 + lr)*2]     = mst;
    Ml[(pr + wid*16 + lr)*2 + 1] = lst;
  }
}

// ------------- flash attention REDUCE: merge 16 chunk partials per row ----
template<bool CAUSAL>
__global__ __launch_bounds__(256) void attn_red_k(const float* __restrict__ Op,
                                                  const float* __restrict__ Ml,
                                                  u16* __restrict__ O){
  int r = blockIdx.x*4 + (threadIdx.x>>6);
  int d = threadIdx.x & 63;
  int qb = r >> 6, rt = r & 63;
  int nch = CAUSAL ? (qb>>3) + 1 : 16;
  long base = (long)qb*16*64 + rt;
  float m = -1e30f;
  for(int i=0;i<nch;i++) m = fmaxf(m, Ml[(base + i*64)*2]);
  float L = 0.f, acc = 0.f;
  for(int i=0;i<nch;i++){
    float mi = Ml[(base + i*64)*2], li = Ml[(base + i*64)*2 + 1];
    float w = exp2f(mi - m);
    L   += li * w;
    acc += w * Op[(base + i*64)*64 + d];
  }
  O[(long)r*HD + d] = f2b(acc / L);
}

extern "C" void kernel_launch(void* const* d_in, const int* in_sizes, int n_in,
                              void* d_out, int out_size, void* d_ws, size_t ws_size,
                              hipStream_t stream){
  const float* enc  = (const float*)d_in[0];
  const float* prev = (const float*)d_in[1];
  const float* wq_m = (const float*)d_in[2];
  const float* wk_m = (const float*)d_in[3];
  const float* wv_m = (const float*)d_in[4];
  const float* wq_c = (const float*)d_in[5];
  const float* wk_c = (const float*)d_in[6];
  const float* wv_c = (const float*)d_in[7];
  const float* w_o  = (const float*)d_in[8];
  const float* ln_g = (const float*)d_in[9];
  const float* ln_b = (const float*)d_in[10];
  const float* w1   = (const float*)d_in[11];
  const float* b1   = (const float*)d_in[12];
  const float* w2   = (const float*)d_in[13];
  const float* b2   = (const float*)d_in[14];
  float* out = (float*)d_out;
  u16* ws  = (u16*)d_ws;

  // workspace layout (u16 element offsets) — total ≈ 76 MB (proven fit)
  u16* wq_m_t = ws;                          // 6 contiguous 32768 blocks
  u16* wk_c_t = wq_m_t + 4*32768;            // (order: qm,km,vm,qc,kc,vc)
  u16* wost   = wq_m_t + 6*32768;
  u16* w1_t   = wost   + 32768;              // 2048*512
  u16* w2_t   = w1_t   + 1048576;            // 512*2048
  u16* enc_b  = w2_t   + 1048576;            // 8192*512 bf16
  u16* prev_b = enc_b  + 4194304;
  u16* q_m    = prev_b + 4194304;            // 8192*64 each
  u16* k_m    = q_m    + 524288;
  u16* v_m    = k_m    + 524288;
  u16* v_m_t  = v_m    + 524288;
  u16* head_m = v_m_t  + 524288;
  u16* k_c    = head_m + 524288;
  u16* v_c    = k_c    + 524288;
  u16* v_c_t  = v_c    + 524288;
  u16* q_c    = v_c_t  + 524288;
  u16* head_c = q_c    + 524288;
  u16* mmh    = head_c + 524288;             // 8192*512
  u16* mh     = mmh    + 4194304;            // 8192*512
  u16* xb     = mh     + 4194304;            // 8192*512 bf16 (LN out for FFN)
  float* xf   = (float*)(xb + 4194304);      // 8192*512 fp32 (LN out residual)
  // aliases over dead/not-yet-live regions:
  u16* hbuf   = enc_b;                       // 8192*2048 bf16 (FFN mid)
  u16* ffn    = mh;                          // 8192*512 (mh dead by then)
  // attention partials: mmh..xf region (41.9 MB) is dead during both attns
  float* Op   = (float*)mmh;                 // 128*16*64*64 fp32 = 33.5 MB
  float* Ml   = Op + (long)128*16*64*64;     // 128*16*64*2 fp32 = 1 MB

  dim3 b256(256), tb(32,8);

  // output 0 passthrough + enc bf16 convert (fused); prev convert
  copycvt_k<<<dim3(2048), b256, 0, stream>>>(enc, out, enc_b, (long)SEQ*DM/8);
  cvt_k<<<dim3(2048), b256, 0, stream>>>(prev, prev_b, (long)SEQ*DM/8);

  // weight prep
  wtrans6_k<<<dim3(2,16,6), tb, 0, stream>>>(wq_m, wk_m, wv_m, wq_c, wk_c, wv_c, wq_m_t);
  transpose_k<1><<<dim3(64,16), tb, 0, stream>>>(w1, w1_t, DM, HFF);
  transpose_k<1><<<dim3(16,64), tb, 0, stream>>>(w2, w2_t, HFF, DM);
  wosum_k<<<dim3(128), b256, 0, stream>>>(w_o, wost);

  // projections: q_m,k_m,v_m = prev @ {..}_m ; k_c,v_c = enc @ {..}_c
  gemm_bt<64,64,2,2,0><<<dim3(SEQ/64,1,3), b256, 0, stream>>>(prev_b, wq_m_t, q_m, nullptr, HD, DM, 32768, 524288);
  gemm_bt<64,64,2,2,0><<<dim3(SEQ/64,1,2), b256, 0, stream>>>(enc_b,  wk_c_t, k_c, nullptr, HD, DM, 32768, 524288);
  vtrans2_k<<<dim3(2,256,2), tb, 0, stream>>>(v_m, v_m_t, v_c, v_c_t);

  // masked self-attention (16-way KV-split) + folded w_o
  attn_part_k<true><<<dim3(SEQ/64, 16), b256, 0, stream>>>(q_m, k_m, v_m_t, Op, Ml);
  attn_red_k<true><<<dim3(SEQ/4), b256, 0, stream>>>(Op, Ml, head_m);
  gemm_bt<64,128,2,2,0><<<dim3(SEQ/64,4,1), b256, 0, stream>>>(head_m, wost, mmh, nullptr, DM, HD, 0, 0);

  // cross attention (16-way KV-split) + folded w_o
  gemm_bt<64,64,2,2,0><<<dim3(SEQ/64,1,1), b256, 0, stream>>>(mmh, wq_m_t + 3*32768, q_c, nullptr, HD, DM, 0, 0);
  attn_part_k<false><<<dim3(SEQ/64, 16), b256, 0, stream>>>(q_c, k_c, v_c_t, Op, Ml);
  attn_red_k<false><<<dim3(SEQ/4), b256, 0, stream>>>(Op, Ml, head_c);
  gemm_bt<64,128,2,2,0><<<dim3(SEQ/64,4,1), b256, 0, stream>>>(head_c, wost, mh, nullptr, DM, HD, 0, 0);

  // x = LN(mh + prev): fp32 out (residual) + bf16 out (FFN input)
  add_ln<true><<<dim3(SEQ/4), b256, 0, stream>>>(mh, prev, ln_g, ln_b, xf, xb);

  // FFN
  gemm_bt<128,128,2,2,2><<<dim3(SEQ/128,HFF/128,1), b256, 0, stream>>>(xb, w1_t, hbuf, b1, HFF, DM, 0, 0);
  gemm_bt<64,128,2,2,1><<<dim3(SEQ/64,4,1),         b256, 0, stream>>>(hbuf, w2_t, ffn, b2, DM, HFF, 0, 0);

  // out1 = LN(ffn + x), fp32
  add_ln<false><<<dim3(SEQ/4), b256, 0, stream>>>(ffn, xf, ln_g, ln_b, out + (long)SEQ*DM, nullptr);
}

// Round 6
// 224.166 us; speedup vs baseline: 2.7278x; 1.2771x over previous
//
#include <hip/hip_runtime.h>
#include <hip/hip_bf16.h>

typedef unsigned short u16;
typedef __attribute__((ext_vector_type(4))) float f32x4;
typedef __attribute__((ext_vector_type(8))) __bf16 bf16x8;
typedef __attribute__((ext_vector_type(8))) short short8;
typedef __attribute__((ext_vector_type(4))) short s16x4;

constexpr int SEQ = 8192;
constexpr int DM  = 512;
constexpr int HD  = 64;
constexpr int HFF = 2048;

__device__ __forceinline__ float b2f(u16 u){
  union { unsigned int i; float f; } v; v.i = ((unsigned int)u) << 16; return v.f;
}
__device__ __forceinline__ u16 f2b(float f){
  union { float f; unsigned int i; } v; v.f = f;
  unsigned int r = v.i + 0x7FFFu + ((v.i >> 16) & 1u);
  return (u16)(r >> 16);
}

// async global->LDS, 16B per lane; LDS base must be wave-uniform.
__device__ __forceinline__ void gload16(const u16* g, u16* lds){
  __builtin_amdgcn_global_load_lds(
      (const __attribute__((address_space(1))) void*)g,
      (__attribute__((address_space(3))) void*)lds, 16, 0, 0);
}

// ------- fused: out0 = enc (fp32 passthrough), enc_b = bf16(enc) ----------
__global__ __launch_bounds__(256) void copycvt_k(const float* __restrict__ in,
                                                 float* __restrict__ outf,
                                                 u16* __restrict__ outb, long n8){
  long i = blockIdx.x * 256L + threadIdx.x;
  if(i >= n8) return;
  f32x4 a = ((const f32x4*)in)[i*2];
  f32x4 b = ((const f32x4*)in)[i*2+1];
  ((f32x4*)outf)[i*2]   = a;
  ((f32x4*)outf)[i*2+1] = b;
  u16 ov[8];
  for(int j=0;j<4;j++){ ov[j] = f2b(a[j]); ov[4+j] = f2b(b[j]); }
  ((short8*)outb)[i] = *(short8*)ov;
}

__global__ __launch_bounds__(256) void cvt_k(const float* __restrict__ in,
                                             u16* __restrict__ out, long n8){
  long i = blockIdx.x * 256L + threadIdx.x;
  if(i >= n8) return;
  f32x4 a = ((const f32x4*)in)[i*2];
  f32x4 b = ((const f32x4*)in)[i*2+1];
  u16 ov[8];
  for(int j=0;j<4;j++){ ov[j] = f2b(a[j]); ov[4+j] = f2b(b[j]); }
  ((short8*)out)[i] = *(short8*)ov;
}

// ------- batched transpose of the six [512,64] projection weights --------
__global__ __launch_bounds__(256) void wtrans6_k(const float* __restrict__ w0,
                                                 const float* __restrict__ w1,
                                                 const float* __restrict__ w2,
                                                 const float* __restrict__ w3,
                                                 const float* __restrict__ w4,
                                                 const float* __restrict__ w5,
                                                 u16* __restrict__ out){
  __shared__ u16 t[32][33];
  const float* ins[6] = {w0,w1,w2,w3,w4,w5};
  const float* in = ins[blockIdx.z];
  u16* o = out + (long)blockIdx.z * 32768;
  int c0 = blockIdx.x*32, r0 = blockIdx.y*32;
  int tx = threadIdx.x, ty = threadIdx.y;     // blockDim (32,8)
  for(int i=0;i<4;i++)
    t[ty+i*8][tx] = f2b(in[(long)(r0+ty+i*8)*HD + c0+tx]);
  __syncthreads();
  for(int i=0;i<4;i++) o[(long)(c0+ty+i*8)*DM + r0+tx] = t[tx][ty+i*8];
}

// ---------------- generic 32x32 transpose; IN_F: 1=fp32 in, 0=bf16 in ----
template<int IN_F>
__global__ __launch_bounds__(256) void transpose_k(const void* __restrict__ inp,
                                                   u16* __restrict__ out, int R, int C){
  __shared__ u16 t[32][33];
  int c0 = blockIdx.x*32, r0 = blockIdx.y*32;
  int tx = threadIdx.x, ty = threadIdx.y;     // blockDim (32,8)
  for(int i=0;i<4;i++){
    long idx = (long)(r0+ty+i*8)*C + c0+tx;
    u16 v;
    if constexpr (IN_F) v = f2b(((const float*)inp)[idx]);
    else                v = ((const u16*)inp)[idx];
    t[ty+i*8][tx] = v;
  }
  __syncthreads();
  for(int i=0;i<4;i++) out[(long)(c0+ty+i*8)*R + r0+tx] = t[tx][ty+i*8];
}

// ------- batched transpose of two [8192,64] V matrices -> [64,8192] ------
__global__ __launch_bounds__(256) void vtrans2_k(const u16* __restrict__ v0,
                                                 u16* __restrict__ o0,
                                                 const u16* __restrict__ v1,
                                                 u16* __restrict__ o1){
  __shared__ u16 t[32][33];
  const u16* in = blockIdx.z ? v1 : v0;
  u16* o = blockIdx.z ? o1 : o0;
  int c0 = blockIdx.x*32, r0 = blockIdx.y*32;
  int tx = threadIdx.x, ty = threadIdx.y;
  for(int i=0;i<4;i++) t[ty+i*8][tx] = in[(long)(r0+ty+i*8)*HD + c0+tx];
  __syncthreads();
  for(int i=0;i<4;i++) o[(long)(c0+ty+i*8)*SEQ + r0+tx] = t[tx][ty+i*8];
}

// ---------------- w_o head-sum, transposed ----------------
__global__ __launch_bounds__(256) void wosum_k(const float* __restrict__ wo,
                                               u16* __restrict__ outT){
  int tid = blockIdx.x*256 + threadIdx.x;     // 32768 total
  int n = tid >> 6, p = tid & 63;
  float s = 0.f;
  for(int h=0; h<8; h++) s += wo[(long)(h*64+p)*DM + n];
  outT[n*64+p] = f2b(s);
}

// ---------------- fused residual-add + LayerNorm ----------------
template<bool WRITE_BF>
__global__ __launch_bounds__(256) void add_ln(const u16* __restrict__ Xa,
                                              const float* __restrict__ Xb,
                                              const float* __restrict__ G,
                                              const float* __restrict__ Bb,
                                              float* __restrict__ OutF,
                                              u16* __restrict__ OutB){
  int row  = blockIdx.x*4 + (threadIdx.x>>6);
  int lane = threadIdx.x & 63;
  short8 a8 = *(const short8*)&Xa[(long)row*DM + lane*8];
  f32x4 b0 = *(const f32x4*)&Xb[(long)row*DM + lane*8];
  f32x4 b1 = *(const f32x4*)&Xb[(long)row*DM + lane*8 + 4];
  float x[8]; float s=0.f, s2=0.f;
  for(int i=0;i<8;i++){
    float bv = (i<4) ? b0[i] : b1[i-4];
    x[i] = b2f((u16)a8[i]) + bv;
    s += x[i]; s2 += x[i]*x[i];
  }
  for(int o=1;o<64;o<<=1){ s += __shfl_xor(s,o); s2 += __shfl_xor(s2,o); }
  float mu  = s * (1.f/DM);
  float var = s2 * (1.f/DM) - mu*mu;
  float rstd = rsqrtf(var + 1e-5f);
  f32x4 g0 = *(const f32x4*)&G[lane*8];
  f32x4 g1 = *(const f32x4*)&G[lane*8+4];
  f32x4 p0 = *(const f32x4*)&Bb[lane*8];
  f32x4 p1 = *(const f32x4*)&Bb[lane*8+4];
  float of[8]; u16 ob[8];
  for(int i=0;i<8;i++){
    float gv = (i<4)?g0[i]:g1[i-4], bv2 = (i<4)?p0[i]:p1[i-4];
    float v = (x[i]-mu)*rstd*gv + bv2;
    of[i] = v; ob[i] = f2b(v);
  }
  *(f32x4*)&OutF[(long)row*DM + lane*8]     = *(f32x4*)&of[0];
  *(f32x4*)&OutF[(long)row*DM + lane*8 + 4] = *(f32x4*)&of[4];
  if constexpr (WRITE_BF)
    *(short8*)&OutB[(long)row*DM + lane*8] = *(short8*)ob;
}

// ---- GEMM v2: global_load_lds staging, source-swizzled LDS, double-buffer
// C[M,N] = epi(A[M,K] @ Bt[N,K]^T + bias); 4 waves (2x2); BK=64.
// LDS linear [rows][64] u16; source col pre-swizzled by ^((row&7)<<4) bytes,
// ds_read applies the same XOR (T2/m201 both-sides pattern).
template<int BM,int BN,int EPI>
__global__ __launch_bounds__(256) void gemm2(const u16* __restrict__ A,
                                             const u16* __restrict__ Bt,
                                             u16* __restrict__ C,
                                             const float* __restrict__ bias,
                                             int N, int K, long sB, long sC){
  constexpr int WR=2, WC=2;
  constexpr int WM = BM/WR, WN = BN/WC;
  constexpr int MF = WM/16, NF = WN/16;
  __shared__ u16 As[2][BM*64];
  __shared__ u16 Bs[2][BN*64];

  const int tid = threadIdx.x;
  const int wid = tid >> 6, lane = tid & 63;
  const int g = lane >> 4, lr = lane & 15;
  const int m0 = blockIdx.x * BM;
  const int n0 = blockIdx.y * BN;
  Bt += (long)blockIdx.z * sB;
  C  += (long)blockIdx.z * sC;
  const int wr = wid / WC, wc = wid % WC;

  f32x4 acc[MF][NF];
  for(int m=0;m<MF;m++) for(int n=0;n<NF;n++) acc[m][n] = (f32x4)0.f;

  // one 1KB chunk = 8 rows x 64 u16; lane's 16B lands at Lb + lane*16 (linear)
  auto stage = [&](const u16* src, int base_row, u16* lds, int rows, int k0){
    const int cpw = rows/32;                   // chunks per wave
    for(int i=0;i<cpw;i++){
      int chunk = wid*cpw + i;
      int Lb = chunk*1024;                     // wave-uniform LDS byte base
      int L  = Lb + lane*16;
      int row = L >> 7, cb = L & 127;
      int scb = cb ^ ((row&7)<<4);             // inverse swizzle on SOURCE
      gload16(&src[(long)(base_row+row)*K + k0 + (scb>>1)], lds + (Lb>>1));
    }
  };

  const int nk = K/64;
  stage(A, m0, As[0], BM, 0);
  stage(Bt, n0, Bs[0], BN, 0);
  __syncthreads();                             // vmcnt(0) drain + barrier
  int cur = 0;
  for(int t=0;t<nk;t++){
    if(t+1<nk){                                // stage-early: overlap with MFMA
      stage(A, m0, As[cur^1], BM, (t+1)*64);
      stage(Bt, n0, Bs[cur^1], BN, (t+1)*64);
    }
    for(int kc=0;kc<2;kc++){
      const int co = (kc*32 + g*8) ^ ((lr&7)<<3);   // swizzled u16 col
      bf16x8 af[MF], bfr[NF];
      for(int m=0;m<MF;m++) af[m]  = *(const bf16x8*)&As[cur][(wr*WM+m*16+lr)*64 + co];
      for(int n=0;n<NF;n++) bfr[n] = *(const bf16x8*)&Bs[cur][(wc*WN+n*16+lr)*64 + co];
      for(int m=0;m<MF;m++)
        for(int n=0;n<NF;n++)
          acc[m][n] = __builtin_amdgcn_mfma_f32_16x16x32_bf16(af[m], bfr[n], acc[m][n], 0,0,0);
    }
    __syncthreads();                           // drains next-tile loads + readers
    cur ^= 1;
  }
  for(int m=0;m<MF;m++){
    int row = m0 + wr*WM + m*16 + g*4;
    for(int n=0;n<NF;n++){
      int col = n0 + wc*WN + n*16 + lr;
      float bv = 0.f;
      if constexpr (EPI>=1) bv = bias[col];
      for(int j=0;j<4;j++){
        float v = acc[m][n][j] + bv;
        if constexpr (EPI==2) v = (v >= 0.f) ? v : 0.01f*v;
        C[(long)(row+j)*N + col] = f2b(v);
      }
    }
  }
}

// ------------- flash attention PARTIAL: (Q-tile 64) x (KV-chunk 512) -----
template<bool CAUSAL>
__global__ __launch_bounds__(256) void attn_part_k(const u16* __restrict__ Q,
                                                   const u16* __restrict__ Km,
                                                   const u16* __restrict__ Vt,
                                                   float* __restrict__ Op,
                                                   float* __restrict__ Ml){
  constexpr int LDK = 72;
  constexpr int NCH = 16;    // chunks of 512
  constexpr int CTI = 8;     // 64-wide tiles per chunk
  __shared__ u16 Ks[64*LDK];
  __shared__ u16 Vs[64*LDK];
  __shared__ u16 Ps[4*16*LDK];

  const int qb = blockIdx.x, ci = blockIdx.y;
  if(CAUSAL && ci*CTI > qb) return;

  const int tid = threadIdx.x, wid = tid>>6, lane = tid&63;
  const int g = lane>>4, lr = lane&15, r4 = g*4;
  const int qrow = qb*64 + wid*16;

  bf16x8 qf[2];
  for(int kc=0;kc<2;kc++){
    bf16x8 t = *(const bf16x8*)&Q[(long)(qrow + lr)*HD + kc*32 + g*8];
    for(int i=0;i<8;i++) t[i] = (__bf16)((float)t[i] * 0.1803368801f);
    qf[kc] = t;
  }

  f32x4 o[4]; for(int n=0;n<4;n++) o[n] = (f32x4)0.f;
  float mst = -1e30f, lst = 0.f;

  const int tdiag = qb - ci*CTI;
  const int tmax = CAUSAL ? min(CTI, tdiag + 1) : CTI;

  const int sr0 = tid>>3, sc0 = (tid&7)*8;
  short8 rK0, rK1, rV0, rV1;
  {
    const int kv0 = ci*512;
    rK0 = *(const short8*)&Km[(long)(kv0+sr0)*HD + sc0];
    rK1 = *(const short8*)&Km[(long)(kv0+sr0+32)*HD + sc0];
    rV0 = *(const short8*)&Vt[(long)sr0*SEQ + kv0 + sc0];
    rV1 = *(const short8*)&Vt[(long)(sr0+32)*SEQ + kv0 + sc0];
  }

  for(int t=0; t<tmax; ++t){
    const int kv0 = ci*512 + t*64;
    __syncthreads();
    *(short8*)&Ks[sr0*LDK + sc0]      = rK0;
    *(short8*)&Ks[(sr0+32)*LDK + sc0] = rK1;
    *(short8*)&Vs[sr0*LDK + sc0]      = rV0;
    *(short8*)&Vs[(sr0+32)*LDK + sc0] = rV1;
    __syncthreads();
    if(t+1 < tmax){
      const int kn = kv0 + 64;
      rK0 = *(const short8*)&Km[(long)(kn+sr0)*HD + sc0];
      rK1 = *(const short8*)&Km[(long)(kn+sr0+32)*HD + sc0];
      rV0 = *(const short8*)&Vt[(long)sr0*SEQ + kn + sc0];
      rV1 = *(const short8*)&Vt[(long)(sr0+32)*SEQ + kn + sc0];
    }

    f32x4 s[4]; for(int n=0;n<4;n++) s[n] = (f32x4)0.f;
    for(int kc=0;kc<2;kc++){
      for(int n=0;n<4;n++){
        bf16x8 kf = *(const bf16x8*)&Ks[(n*16+lr)*LDK + kc*32 + g*8];
        s[n] = __builtin_amdgcn_mfma_f32_16x16x32_bf16(kf, qf[kc], s[n], 0,0,0);
      }
    }
    if(CAUSAL && t == tdiag){
      int row = qrow + lr;
      for(int n=0;n<4;n++)
        for(int j=0;j<4;j++)
          if(kv0 + n*16 + r4 + j > row) s[n][j] = -1e30f;
    }
    float pmax = s[0][0];
    for(int n=0;n<4;n++)
      for(int j=0;j<4;j++) pmax = fmaxf(pmax, s[n][j]);
    pmax = fmaxf(pmax, __shfl_xor(pmax,16));
    pmax = fmaxf(pmax, __shfl_xor(pmax,32));
    if(__any(pmax > mst + 8.f)){
      float mn = fmaxf(mst, pmax);
      float fac = exp2f(mst - mn);
      mst = mn; lst *= fac;
      float fj0 = __shfl(fac, r4+0), fj1 = __shfl(fac, r4+1);
      float fj2 = __shfl(fac, r4+2), fj3 = __shfl(fac, r4+3);
      for(int n=0;n<4;n++){
        o[n][0] *= fj0; o[n][1] *= fj1; o[n][2] *= fj2; o[n][3] *= fj3;
      }
    }
    float rs = 0.f;
    for(int n=0;n<4;n++){
      u16 w[4];
      for(int j=0;j<4;j++){
        float p = exp2f(s[n][j] - mst);
        rs += p;
        __bf16 pb = (__bf16)p;
        union { __bf16 b; u16 u; } cv; cv.b = pb;
        w[j] = cv.u;
      }
      *(s16x4*)&Ps[(wid*16 + lr)*LDK + n*16 + r4] = *(s16x4*)w;
    }
    rs += __shfl_xor(rs,16); rs += __shfl_xor(rs,32);
    lst += rs;
    for(int kc=0;kc<2;kc++){
      bf16x8 pf = *(const bf16x8*)&Ps[(wid*16 + lr)*LDK + kc*32 + g*8];
      for(int n=0;n<4;n++){
        bf16x8 vf = *(const bf16x8*)&Vs[(n*16+lr)*LDK + kc*32 + g*8];
        o[n] = __builtin_amdgcn_mfma_f32_16x16x32_bf16(pf, vf, o[n], 0,0,0);
      }
    }
  }
  const long pr = (long)(qb*NCH + ci)*64;
  for(int n=0;n<4;n++)
    for(int j=0;j<4;j++)
      Op[(pr + wid*16 + r4 + j)*64 + n*16 + lr] = o[n][j];
  if(lane < 16){
    Ml[(pr + wid*16 + lr)*2]     = mst;
    Ml[(pr + wid*16 + lr)*2 + 1] = lst;
  }
}

// ------------- flash attention REDUCE: merge 16 chunk partials per row ----
template<bool CAUSAL>
__global__ __launch_bounds__(256) void attn_red_k(const float* __restrict__ Op,
                                                  const float* __restrict__ Ml,
                                                  u16* __restrict__ O){
  int r = blockIdx.x*4 + (threadIdx.x>>6);
  int d = threadIdx.x & 63;
  int qb = r >> 6, rt = r & 63;
  int nch = CAUSAL ? (qb>>3) + 1 : 16;
  long base = (long)qb*16*64 + rt;
  float m = -1e30f;
  for(int i=0;i<nch;i++) m = fmaxf(m, Ml[(base + i*64)*2]);
  float L = 0.f, acc = 0.f;
  for(int i=0;i<nch;i++){
    float mi = Ml[(base + i*64)*2], li = Ml[(base + i*64)*2 + 1];
    float w = exp2f(mi - m);
    L   += li * w;
    acc += w * Op[(base + i*64)*64 + d];
  }
  O[(long)r*HD + d] = f2b(acc / L);
}

extern "C" void kernel_launch(void* const* d_in, const int* in_sizes, int n_in,
                              void* d_out, int out_size, void* d_ws, size_t ws_size,
                              hipStream_t stream){
  const float* enc  = (const float*)d_in[0];
  const float* prev = (const float*)d_in[1];
  const float* wq_m = (const float*)d_in[2];
  const float* wk_m = (const float*)d_in[3];
  const float* wv_m = (const float*)d_in[4];
  const float* wq_c = (const float*)d_in[5];
  const float* wk_c = (const float*)d_in[6];
  const float* wv_c = (const float*)d_in[7];
  const float* w_o  = (const float*)d_in[8];
  const float* ln_g = (const float*)d_in[9];
  const float* ln_b = (const float*)d_in[10];
  const float* w1   = (const float*)d_in[11];
  const float* b1   = (const float*)d_in[12];
  const float* w2   = (const float*)d_in[13];
  const float* b2   = (const float*)d_in[14];
  float* out = (float*)d_out;
  u16* ws  = (u16*)d_ws;

  // workspace layout (u16 element offsets) — total ≈ 76 MB (proven fit)
  u16* wq_m_t = ws;                          // 6 contiguous 32768 blocks
  u16* wk_c_t = wq_m_t + 4*32768;
  u16* wost   = wq_m_t + 6*32768;
  u16* w1_t   = wost   + 32768;              // 2048*512
  u16* w2_t   = w1_t   + 1048576;            // 512*2048
  u16* enc_b  = w2_t   + 1048576;            // 8192*512 bf16
  u16* prev_b = enc_b  + 4194304;
  u16* q_m    = prev_b + 4194304;            // 8192*64 each
  u16* k_m    = q_m    + 524288;
  u16* v_m    = k_m    + 524288;
  u16* v_m_t  = v_m    + 524288;
  u16* head_m = v_m_t  + 524288;
  u16* k_c    = head_m + 524288;
  u16* v_c    = k_c    + 524288;
  u16* v_c_t  = v_c    + 524288;
  u16* q_c    = v_c_t  + 524288;
  u16* head_c = q_c    + 524288;
  u16* mmh    = head_c + 524288;             // 8192*512
  u16* mh     = mmh    + 4194304;            // 8192*512
  u16* xb     = mh     + 4194304;            // 8192*512 bf16 (LN out for FFN)
  float* xf   = (float*)(xb + 4194304);      // 8192*512 fp32 (LN out residual)
  u16* hbuf   = enc_b;                       // 8192*2048 bf16 (FFN mid)
  u16* ffn    = mh;                          // 8192*512 (mh dead by then)
  float* Op   = (float*)mmh;                 // 128*16*64*64 fp32 = 33.5 MB
  float* Ml   = Op + (long)128*16*64*64;     // 128*16*64*2 fp32 = 1 MB

  dim3 b256(256), tb(32,8);

  copycvt_k<<<dim3(2048), b256, 0, stream>>>(enc, out, enc_b, (long)SEQ*DM/8);
  cvt_k<<<dim3(2048), b256, 0, stream>>>(prev, prev_b, (long)SEQ*DM/8);

  wtrans6_k<<<dim3(2,16,6), tb, 0, stream>>>(wq_m, wk_m, wv_m, wq_c, wk_c, wv_c, wq_m_t);
  transpose_k<1><<<dim3(64,16), tb, 0, stream>>>(w1, w1_t, DM, HFF);
  transpose_k<1><<<dim3(16,64), tb, 0, stream>>>(w2, w2_t, HFF, DM);
  wosum_k<<<dim3(128), b256, 0, stream>>>(w_o, wost);

  // projections: q_m,k_m,v_m = prev @ {..}_m ; k_c,v_c = enc @ {..}_c
  gemm2<64,64,0><<<dim3(SEQ/64,1,3), b256, 0, stream>>>(prev_b, wq_m_t, q_m, nullptr, HD, DM, 32768, 524288);
  gemm2<64,64,0><<<dim3(SEQ/64,1,2), b256, 0, stream>>>(enc_b,  wk_c_t, k_c, nullptr, HD, DM, 32768, 524288);
  vtrans2_k<<<dim3(2,256,2), tb, 0, stream>>>(v_m, v_m_t, v_c, v_c_t);

  // masked self-attention (16-way KV-split) + folded w_o
  attn_part_k<true><<<dim3(SEQ/64, 16), b256, 0, stream>>>(q_m, k_m, v_m_t, Op, Ml);
  attn_red_k<true><<<dim3(SEQ/4), b256, 0, stream>>>(Op, Ml, head_m);
  gemm2<64,128,0><<<dim3(SEQ/64,4,1), b256, 0, stream>>>(head_m, wost, mmh, nullptr, DM, HD, 0, 0);

  // cross attention (16-way KV-split) + folded w_o
  gemm2<64,64,0><<<dim3(SEQ/64,1,1), b256, 0, stream>>>(mmh, wq_m_t + 3*32768, q_c, nullptr, HD, DM, 0, 0);
  attn_part_k<false><<<dim3(SEQ/64, 16), b256, 0, stream>>>(q_c, k_c, v_c_t, Op, Ml);
  attn_red_k<false><<<dim3(SEQ/4), b256, 0, stream>>>(Op, Ml, head_c);
  gemm2<64,128,0><<<dim3(SEQ/64,4,1), b256, 0, stream>>>(head_c, wost, mh, nullptr, DM, HD, 0, 0);

  // x = LN(mh + prev): fp32 out (residual) + bf16 out (FFN input)
  add_ln<true><<<dim3(SEQ/4), b256, 0, stream>>>(mh, prev, ln_g, ln_b, xf, xb);

  // FFN
  gemm2<128,128,2><<<dim3(SEQ/128,HFF/128,1), b256, 0, stream>>>(xb, w1_t, hbuf, b1, HFF, DM, 0, 0);
  gemm2<64,128,1><<<dim3(SEQ/64,4,1),         b256, 0, stream>>>(hbuf, w2_t, ffn, b2, DM, HFF, 0, 0);

  // out1 = LN(ffn + x), fp32
  add_ln<false><<<dim3(SEQ/4), b256, 0, stream>>>(ffn, xf, ln_g, ln_b, out + (long)SEQ*DM, nullptr);
}